// Round 6
// baseline (142.925 us; speedup 1.0000x reference)
//
#include <hip/hip_runtime.h>

// Playlist model: gathers -> concat [B,1920] -> low-rank cross -> MLP -> L2 norm.
// bf16 MFMA GEMMs (16x16x32), fp32 accumulate, double-buffered LDS prefetch,
// XCD-bijective block swizzle, fused tail (h1/h2/l2norm in LDS).

constexpr int B_ = 8192;
constexpr int D_ = 128;
constexpr int L_ = 5;
constexpr int F_ = 1920;   // 15 * 128
constexpr int P_ = 100;    // cross rank (padded to 128)

typedef __attribute__((ext_vector_type(8))) short short8;
typedef __attribute__((ext_vector_type(4))) float f32x4;
typedef __attribute__((ext_vector_type(4))) unsigned short u16x4;

__device__ __forceinline__ unsigned short f2bf(float x) {
  union { float f; unsigned int u; } v; v.f = x;
  unsigned int r = v.u + 0x7FFF + ((v.u >> 16) & 1);   // RNE
  return (unsigned short)(r >> 16);
}
__device__ __forceinline__ float bf2f(unsigned short b) {
  union { unsigned int u; float f; } v; v.u = ((unsigned int)b) << 16;
  return v.f;
}

__device__ __forceinline__ void gload_lds16(const void* g, void* l) {
  __builtin_amdgcn_global_load_lds(
      (const __attribute__((address_space(1))) void*)g,
      (__attribute__((address_space(3))) void*)l, 16, 0, 0);
}

// ---------------- gather + pool -> X (bf16 [B,1920]) ----------------
struct GatherArgs {
  const int*   idx[15];
  const float* tab[15];
};

__global__ __launch_bounds__(256)
void gather_pool_kernel(GatherArgs ga, unsigned short* __restrict__ X) {
  const int g = threadIdx.x >> 5;          // row group 0..7
  const int c = threadIdx.x & 31;          // float4 chunk 0..31
  const int b = blockIdx.x * 8 + g;
  unsigned short* xr = X + (size_t)b * F_;
#pragma unroll
  for (int s = 0; s < 6; ++s) {
    const int i = ga.idx[s][b];
    const float4 e = ((const float4*)(ga.tab[s] + (size_t)i * D_))[c];
    u16x4 o; o[0] = f2bf(e.x); o[1] = f2bf(e.y); o[2] = f2bf(e.z); o[3] = f2bf(e.w);
    *(u16x4*)(xr + s * D_ + c * 4) = o;
  }
#pragma unroll
  for (int s = 6; s < 15; ++s) {
    const bool masked = (s < 11) || (s == 14);   // 11..13 plain mean
    const int* ip = ga.idx[s] + b * L_;
    float sx = 0.f, sy = 0.f, sz = 0.f, sw = 0.f, cnt = 0.f;
#pragma unroll
    for (int l = 0; l < L_; ++l) {
      const int i = ip[l];
      const float4 e = ((const float4*)(ga.tab[s] + (size_t)i * D_))[c];
      if (!masked || i != 0) { sx += e.x; sy += e.y; sz += e.z; sw += e.w; cnt += 1.f; }
    }
    const float inv = 1.f / (masked ? fmaxf(cnt, 1.f) : (float)L_);
    u16x4 o; o[0] = f2bf(sx * inv); o[1] = f2bf(sy * inv);
    o[2] = f2bf(sz * inv); o[3] = f2bf(sw * inv);
    *(u16x4*)(xr + s * D_ + c * 4) = o;
  }
}

// ------------- fused transpose + pad fp32 -> bf16 (all 5 weights) -------------
struct TransBatch {
  const float* src[5];
  unsigned short* dst[5];
  int R[5], C[5], Cpad[5], Rpad[5], tiles_c[5], tile0[6];
};

__global__ __launch_bounds__(256)
void transpose_pad_all(TransBatch tb) {
  __shared__ float tile[32][33];
  const int id = blockIdx.x;
  int d = 0;
#pragma unroll
  for (int i = 1; i < 5; ++i) if (id >= tb.tile0[i]) d = i;
  const int lid = id - tb.tile0[d];
  const int tcn = tb.tiles_c[d];
  const int tr = lid / tcn, tc = lid - tr * tcn;
  const float* src = tb.src[d];
  unsigned short* dst = tb.dst[d];
  const int R = tb.R[d], C = tb.C[d], Cpad = tb.Cpad[d], Rpad = tb.Rpad[d];
  const int r0 = tr * 32, c0 = tc * 32;
  const int tx = threadIdx.x & 31, ty = threadIdx.x >> 5;  // 32 x 8
#pragma unroll
  for (int i = 0; i < 32; i += 8) {
    const int r = r0 + ty + i, c = c0 + tx;
    tile[ty + i][tx] = (r < R && c < C) ? src[(size_t)r * C + c] : 0.f;
  }
  __syncthreads();
#pragma unroll
  for (int i = 0; i < 32; i += 8) {
    const int c = c0 + ty + i, r = r0 + tx;
    if (c < Cpad && r < Rpad)
      dst[(size_t)c * Rpad + r] = f2bf(tile[tx][ty + i]);
  }
}

// ---------------- bf16 MFMA GEMM: C[M,N] = A[M,K] @ Bt[N,K]^T ----------------
// BMxBN tile, BK=64, 4 waves (2x2), DBUF = double-buffered LDS prefetch.
// EPI: 0 = +bias -> fp32 | 1 = +bias,ReLU -> bf16 | 2 = pad-store -> bf16 (col<Nvalid else 0)
//      3 = cross: x*(acc+bias)+x -> bf16 in place (Cb is both input x and output)
template<int EPI, int BM, int BN, bool DBUF>
__global__ __launch_bounds__(256)
void mfma_gemm(const unsigned short* __restrict__ A, const unsigned short* __restrict__ Bt,
               const float* __restrict__ bias, float* __restrict__ Cf,
               unsigned short* __restrict__ Cb, int M, int N, int K, int Nvalid)
{
  constexpr int BK = 64;
  constexpr int NB = DBUF ? 2 : 1;
  constexpr int WM = BM / 2, WN = BN / 2;
  constexpr int NFM = WM / 16, NFN = WN / 16;
  __shared__ __align__(16) unsigned short As[NB][BM * BK];
  __shared__ __align__(16) unsigned short Bs[NB][BN * BK];

  // XCD-bijective swizzle (requires gridDim.x*gridDim.y % 8 == 0)
  const int nwg  = gridDim.x * gridDim.y;
  const int wgid = blockIdx.y * gridDim.x + blockIdx.x;
  const int q    = nwg >> 3;
  const int sid  = (wgid & 7) * q + (wgid >> 3);
  const int bx   = sid % gridDim.x, by = sid / gridDim.x;

  const int tid  = threadIdx.x;
  const int wave = tid >> 6, lane = tid & 63;
  const int row0 = by * BM;
  const int n0   = bx * BN;
  const int wr = (wave >> 1) * WM, wc = (wave & 1) * WN;
  const int srow = lane >> 3;
  const int gc   = (lane & 7) ^ srow;

  f32x4 acc[NFM][NFN];
#pragma unroll
  for (int m = 0; m < NFM; ++m)
#pragma unroll
    for (int n = 0; n < NFN; ++n)
      acc[m][n] = (f32x4){0.f, 0.f, 0.f, 0.f};

  const size_t abase = (size_t)(row0 + srow) * K + (size_t)gc * 8;
  const size_t bbase = (size_t)(n0   + srow) * K + (size_t)gc * 8;

  auto stage = [&](int buf, int k0) {
#pragma unroll
    for (int i = 0; i < BM / 32; ++i) {
      const int s = wave * (BM / 32) + i;
      gload_lds16(A + abase + (size_t)s * 8 * K + k0, As[buf] + s * 512);
    }
#pragma unroll
    for (int i = 0; i < BN / 32; ++i) {
      const int s = wave * (BN / 32) + i;
      gload_lds16(Bt + bbase + (size_t)s * 8 * K + k0, Bs[buf] + s * 512);
    }
  };

  auto compute = [&](int buf) {
#pragma unroll
    for (int ks = 0; ks < 2; ++ks) {
      short8 af[NFM], bfr[NFN];
#pragma unroll
      for (int m = 0; m < NFM; ++m) {
        const int r  = wr + m * 16 + (lane & 15);
        const int cs = (ks * 4 + (lane >> 4)) ^ (r & 7);
        af[m] = *(const short8*)(As[buf] + r * 64 + cs * 8);
      }
#pragma unroll
      for (int n = 0; n < NFN; ++n) {
        const int r  = wc + n * 16 + (lane & 15);
        const int cs = (ks * 4 + (lane >> 4)) ^ (r & 7);
        bfr[n] = *(const short8*)(Bs[buf] + r * 64 + cs * 8);
      }
#pragma unroll
      for (int m = 0; m < NFM; ++m)
#pragma unroll
        for (int n = 0; n < NFN; ++n)
          acc[m][n] = __builtin_amdgcn_mfma_f32_16x16x32_bf16(af[m], bfr[n], acc[m][n], 0, 0, 0);
    }
  };

  const int nk = K / BK;
  if (!DBUF) {
    for (int t = 0; t < nk; ++t) {
      stage(0, t * BK);
      __syncthreads();
      compute(0);
      __syncthreads();
    }
  } else {
    stage(0, 0);
    __syncthreads();
    int cur = 0;
    for (int t = 0; t + 1 < nk; ++t) {
      stage(cur ^ 1, (t + 1) * BK);
      compute(cur);
      __syncthreads();
      cur ^= 1;
    }
    compute(cur);
  }

  const int l15 = lane & 15, l4 = lane >> 4;
#pragma unroll
  for (int m = 0; m < NFM; ++m) {
#pragma unroll
    for (int n = 0; n < NFN; ++n) {
      const int col = n0 + wc + n * 16 + l15;
      const float bv = (EPI == 2) ? 0.f : bias[col];
#pragma unroll
      for (int r = 0; r < 4; ++r) {
        const int row = row0 + wr + m * 16 + l4 * 4 + r;
        const float v = acc[m][n][r];
        if (EPI == 0) {
          Cf[(size_t)row * N + col] = v + bv;
        } else if (EPI == 1) {
          Cb[(size_t)row * N + col] = f2bf(fmaxf(v + bv, 0.f));
        } else if (EPI == 2) {
          Cb[(size_t)row * N + col] = (col < Nvalid) ? f2bf(v) : (unsigned short)0;
        } else {
          const float x = bf2f(Cb[(size_t)row * N + col]);
          Cb[(size_t)row * N + col] = f2bf(fmaf(x, v + bv, x));
        }
      }
    }
  }
}

// ------- fused tail: h1=relu(h0@W1+b1); h2=h1@W2+b2; l2norm -> out -------
// 32 rows/block, 512 threads = 8 waves (1x8 col split -> W1 read once/block).
__global__ __launch_bounds__(512)
void tail_kernel(const unsigned short* __restrict__ h0,   // [B][512] bf16
                 const unsigned short* __restrict__ Wt1,  // [256][512]
                 const float* __restrict__ b1,
                 const unsigned short* __restrict__ Wt2,  // [128][256]
                 const float* __restrict__ b2,
                 float* __restrict__ out)                  // [B][128]
{
  __shared__ __align__(16) unsigned short As[2][32 * 64]; // h0 K-tiles (dbuf)
  __shared__ __align__(16) unsigned short H1[32 * 256];   // h1 bf16 swizzled
  __shared__ float H2[32 * 128];                          // h2 fp32
  const int tid  = threadIdx.x;
  const int wave = tid >> 6, lane = tid & 63;
  const int l15 = lane & 15, l4 = lane >> 4;
  const int r0 = blockIdx.x * 32;

  // staging (waves 0..3): slot=wave covers rows 8*wave..8*wave+7
  const int srow = (wave & 3) * 8 + (lane >> 3);
  const int gc   = (lane & 7) ^ (srow & 7);
  const size_t abase = (size_t)(r0 + srow) * 512 + (size_t)gc * 8;

  // ---- phase A: h1[32][256] = relu(h0[32][512] @ W1 + b1), wave -> 32 cols ----
  {
    const int wc = wave * 32;
    f32x4 acc[2][2];
#pragma unroll
    for (int m = 0; m < 2; ++m)
#pragma unroll
      for (int n = 0; n < 2; ++n) acc[m][n] = (f32x4){0.f, 0.f, 0.f, 0.f};

    if (wave < 4) gload_lds16(h0 + abase + 0, As[0] + (wave & 3) * 512);
    __syncthreads();
    int cur = 0;
#pragma unroll
    for (int t = 0; t < 8; ++t) {
      if (t + 1 < 8 && wave < 4)
        gload_lds16(h0 + abase + (t + 1) * 64, As[cur ^ 1] + (wave & 3) * 512);
#pragma unroll
      for (int ks = 0; ks < 2; ++ks) {
        short8 af[2];
#pragma unroll
        for (int m = 0; m < 2; ++m) {
          const int r  = m * 16 + l15;
          const int cs = (ks * 4 + l4) ^ (r & 7);
          af[m] = *(const short8*)(As[cur] + r * 64 + cs * 8);
        }
#pragma unroll
        for (int n = 0; n < 2; ++n) {
          const int col = wc + n * 16 + l15;
          const short8 bf = *(const short8*)(Wt1 + (size_t)col * 512 + t * 64 + ks * 32 + l4 * 8);
#pragma unroll
          for (int m = 0; m < 2; ++m)
            acc[m][n] = __builtin_amdgcn_mfma_f32_16x16x32_bf16(af[m], bf, acc[m][n], 0, 0, 0);
        }
      }
      __syncthreads();
      cur ^= 1;
    }
#pragma unroll
    for (int n = 0; n < 2; ++n) {
      const int col = wc + n * 16 + l15;
      const float bv = b1[col];
#pragma unroll
      for (int m = 0; m < 2; ++m) {
#pragma unroll
        for (int r = 0; r < 4; ++r) {
          const int row = m * 16 + l4 * 4 + r;
          const int sc  = ((col >> 3) ^ (row & 7)) * 8 + (col & 7);
          H1[row * 256 + sc] = f2bf(fmaxf(acc[m][n][r] + bv, 0.f));
        }
      }
    }
  }
  __syncthreads();

  // ---- phase B: h2[32][128] = h1 @ W2 + b2, wave -> 16 cols ----
  {
    const int wc = wave * 16;
    f32x4 acc[2];
    acc[0] = (f32x4){0.f, 0.f, 0.f, 0.f};
    acc[1] = (f32x4){0.f, 0.f, 0.f, 0.f};
#pragma unroll
    for (int ks = 0; ks < 8; ++ks) {
      short8 af[2];
#pragma unroll
      for (int m = 0; m < 2; ++m) {
        const int r = m * 16 + l15;
        const int q = (ks * 4 + l4) ^ (r & 7);
        af[m] = *(const short8*)(H1 + r * 256 + q * 8);
      }
      const int col = wc + l15;
      const short8 bf = *(const short8*)(Wt2 + (size_t)col * 256 + ks * 32 + l4 * 8);
#pragma unroll
      for (int m = 0; m < 2; ++m)
        acc[m] = __builtin_amdgcn_mfma_f32_16x16x32_bf16(af[m], bf, acc[m], 0, 0, 0);
    }
    const int col = wc + l15;
    const float bv = b2[col];
#pragma unroll
    for (int m = 0; m < 2; ++m)
#pragma unroll
      for (int r = 0; r < 4; ++r) {
        const int row = m * 16 + l4 * 4 + r;
        H2[row * 128 + col] = acc[m][r] + bv;
      }
  }
  __syncthreads();

  // ---- l2norm: out[row] = h2 * rsqrt(max(sum h2^2, 1e-12)) ----
  {
    const int row = tid >> 4;        // 0..31
    const int seg = tid & 15;        // 8 elems each
    const float* hr = H2 + row * 128;
    float s = 0.f;
    float v[8];
#pragma unroll
    for (int j = 0; j < 8; ++j) { v[j] = hr[seg * 8 + j]; s += v[j] * v[j]; }
#pragma unroll
    for (int off = 8; off; off >>= 1) s += __shfl_xor(s, off, 16);
    const float rs = rsqrtf(fmaxf(s, 1e-12f));
    float* op = out + (size_t)(r0 + row) * 128 + seg * 8;
#pragma unroll
    for (int j = 0; j < 8; ++j) op[j] = v[j] * rs;
  }
}

extern "C" void kernel_launch(void* const* d_in, const int* in_sizes, int n_in,
                              void* d_out, int out_size, void* d_ws, size_t ws_size,
                              hipStream_t stream)
{
  GatherArgs ga;
  for (int s = 0; s < 15; ++s) {
    ga.idx[s] = (const int*)d_in[s];
    ga.tab[s] = (const float*)d_in[15 + s];
  }
  const float* cross_V = (const float*)d_in[30];  // [1920,100]
  const float* cross_U = (const float*)d_in[31];  // [100,1920]
  const float* cross_b = (const float*)d_in[32];  // [1920]
  const float* W0 = (const float*)d_in[33];       // [1920,512]
  const float* b0 = (const float*)d_in[34];
  const float* W1 = (const float*)d_in[35];       // [512,256]
  const float* b1 = (const float*)d_in[36];
  const float* W2 = (const float*)d_in[37];       // [256,128]
  const float* b2 = (const float*)d_in[38];

  char* w = (char*)d_ws;
  unsigned short* Xb  = (unsigned short*)w; w += (size_t)B_ * F_ * 2;    // [8192,1920] bf16
  unsigned short* t   = (unsigned short*)w; w += (size_t)B_ * 128 * 2;   // [8192,128] bf16 (pad 100->128)
  unsigned short* h0  = (unsigned short*)w; w += (size_t)B_ * 512 * 2;   // [8192,512] bf16
  unsigned short* Vt  = (unsigned short*)w; w += (size_t)128 * F_ * 2;   // [128,1920]
  unsigned short* Ut  = (unsigned short*)w; w += (size_t)F_ * 128 * 2;   // [1920,128]
  unsigned short* Wt0 = (unsigned short*)w; w += (size_t)512 * F_ * 2;   // [512,1920]
  unsigned short* Wt1 = (unsigned short*)w; w += (size_t)256 * 512 * 2;  // [256,512]
  unsigned short* Wt2 = (unsigned short*)w; w += (size_t)128 * 256 * 2;  // [128,256]

  const dim3 tb(256);

  // fused weight transposes (fp32 -> bf16, K-major, zero-padded)
  TransBatch tbt;
  const float* srcs[5] = {cross_V, cross_U, W0, W1, W2};
  unsigned short* dsts[5] = {Vt, Ut, Wt0, Wt1, Wt2};
  const int Rs[5]  = {F_, P_, F_, 512, 256};
  const int Cs[5]  = {P_, F_, 512, 256, 128};
  const int Cp[5]  = {128, F_, 512, 256, 128};
  const int Rp[5]  = {F_, 128, F_, 512, 256};
  int acc_t = 0;
  for (int i = 0; i < 5; ++i) {
    tbt.src[i] = srcs[i]; tbt.dst[i] = dsts[i];
    tbt.R[i] = Rs[i]; tbt.C[i] = Cs[i]; tbt.Cpad[i] = Cp[i]; tbt.Rpad[i] = Rp[i];
    tbt.tiles_c[i] = Cp[i] / 32;
    tbt.tile0[i] = acc_t;
    acc_t += (Rp[i] / 32) * (Cp[i] / 32);
  }
  tbt.tile0[5] = acc_t;
  transpose_pad_all<<<acc_t, tb, 0, stream>>>(tbt);

  // 1) gather + pool -> Xb
  gather_pool_kernel<<<B_ / 8, tb, 0, stream>>>(ga, Xb);
  // 2) t = Xb @ V            [8192,128(100 valid)]   grid 2x256=512
  mfma_gemm<2, 32, 64, true><<<dim3(2, B_ / 32), tb, 0, stream>>>(
      Xb, Vt, nullptr, nullptr, t, B_, 128, F_, P_);
  // 3) Xb = x*(t @ U + b)+x  [8192,1920] in place    grid 15x64=960 (K=128: no dbuf)
  mfma_gemm<3, 128, 128, false><<<dim3(F_ / 128, B_ / 128), tb, 0, stream>>>(
      t, Ut, cross_b, nullptr, Xb, B_, F_, 128, F_);
  // 4) h0 = relu(Xb @ W0 + b0)   [8192,512]  grid 8x64=512 (BM=128 halves W0 L2 traffic)
  mfma_gemm<1, 128, 64, true><<<dim3(512 / 64, B_ / 128), tb, 0, stream>>>(
      Xb, Wt0, b0, nullptr, h0, B_, 512, F_, 512);
  // 5+6+7) fused tail: relu(h0@W1+b1)@W2+b2 -> l2norm -> out   grid 256 x 512thr
  tail_kernel<<<B_ / 32, 512, 0, stream>>>(h0, Wt1, b1, Wt2, b2, (float*)d_out);
}

// Round 7
// 129.987 us; speedup vs baseline: 1.0995x; 1.0995x over previous
//
#include <hip/hip_runtime.h>

// Playlist model: gathers -> concat [B,1920] -> low-rank cross -> MLP -> L2 norm.
// bf16 MFMA GEMMs (16x16x32), fp32 accumulate, double-buffered LDS prefetch,
// XCD-bijective block swizzle.  Round-5 structure + transposes merged into the
// gather launch (they hide inside the gather's memory-latency window).

constexpr int B_ = 8192;
constexpr int D_ = 128;
constexpr int L_ = 5;
constexpr int F_ = 1920;   // 15 * 128
constexpr int P_ = 100;    // cross rank (padded to 128)

typedef __attribute__((ext_vector_type(8))) short short8;
typedef __attribute__((ext_vector_type(4))) float f32x4;
typedef __attribute__((ext_vector_type(4))) unsigned short u16x4;

__device__ __forceinline__ unsigned short f2bf(float x) {
  union { float f; unsigned int u; } v; v.f = x;
  unsigned int r = v.u + 0x7FFF + ((v.u >> 16) & 1);   // RNE
  return (unsigned short)(r >> 16);
}
__device__ __forceinline__ float bf2f(unsigned short b) {
  union { unsigned int u; float f; } v; v.u = ((unsigned int)b) << 16;
  return v.f;
}

__device__ __forceinline__ void gload_lds16(const void* g, void* l) {
  __builtin_amdgcn_global_load_lds(
      (const __attribute__((address_space(1))) void*)g,
      (__attribute__((address_space(3))) void*)l, 16, 0, 0);
}

// ---------------- gather + pool + weight transposes (one launch) ----------------
struct GatherArgs {
  const int*   idx[15];
  const float* tab[15];
};
struct TransBatch {
  const float* src[5];
  unsigned short* dst[5];
  int R[5], C[5], Cpad[5], Rpad[5], tiles_c[5], tile0[6];
};

constexpr int NGATHER = B_ / 8;   // 1024 gather blocks (8 rows each)

__global__ __launch_bounds__(256)
void prep_kernel(GatherArgs ga, unsigned short* __restrict__ X, TransBatch tb) {
  __shared__ float tile[32][33];
  if ((int)blockIdx.x < NGATHER) {
    // ---- gather + pool: 8 batch rows, 32 lanes = one float4 chunk each ----
    const int g = threadIdx.x >> 5;
    const int c = threadIdx.x & 31;
    const int b = blockIdx.x * 8 + g;
    unsigned short* xr = X + (size_t)b * F_;
#pragma unroll
    for (int s = 0; s < 6; ++s) {
      const int i = ga.idx[s][b];
      const float4 e = ((const float4*)(ga.tab[s] + (size_t)i * D_))[c];
      u16x4 o; o[0] = f2bf(e.x); o[1] = f2bf(e.y); o[2] = f2bf(e.z); o[3] = f2bf(e.w);
      *(u16x4*)(xr + s * D_ + c * 4) = o;
    }
#pragma unroll
    for (int s = 6; s < 15; ++s) {
      const bool masked = (s < 11) || (s == 14);   // 11..13 plain mean
      const int* ip = ga.idx[s] + b * L_;
      float sx = 0.f, sy = 0.f, sz = 0.f, sw = 0.f, cnt = 0.f;
#pragma unroll
      for (int l = 0; l < L_; ++l) {
        const int i = ip[l];
        const float4 e = ((const float4*)(ga.tab[s] + (size_t)i * D_))[c];
        if (!masked || i != 0) { sx += e.x; sy += e.y; sz += e.z; sw += e.w; cnt += 1.f; }
      }
      const float inv = 1.f / (masked ? fmaxf(cnt, 1.f) : (float)L_);
      u16x4 o; o[0] = f2bf(sx * inv); o[1] = f2bf(sy * inv);
      o[2] = f2bf(sz * inv); o[3] = f2bf(sw * inv);
      *(u16x4*)(xr + s * D_ + c * 4) = o;
    }
  } else {
    // ---- transpose+pad fp32 -> bf16: dst[c][r] = src[r][c] ----
    const int id = blockIdx.x - NGATHER;
    int d = 0;
#pragma unroll
    for (int i = 1; i < 5; ++i) if (id >= tb.tile0[i]) d = i;
    const int lid = id - tb.tile0[d];
    const int tcn = tb.tiles_c[d];
    const int tr = lid / tcn, tc = lid - tr * tcn;
    const float* src = tb.src[d];
    unsigned short* dst = tb.dst[d];
    const int R = tb.R[d], C = tb.C[d], Cpad = tb.Cpad[d], Rpad = tb.Rpad[d];
    const int r0 = tr * 32, c0 = tc * 32;
    const int tx = threadIdx.x & 31, ty = threadIdx.x >> 5;  // 32 x 8
#pragma unroll
    for (int i = 0; i < 32; i += 8) {
      const int r = r0 + ty + i, c = c0 + tx;
      tile[ty + i][tx] = (r < R && c < C) ? src[(size_t)r * C + c] : 0.f;
    }
    __syncthreads();
#pragma unroll
    for (int i = 0; i < 32; i += 8) {
      const int c = c0 + ty + i, r = r0 + tx;
      if (c < Cpad && r < Rpad)
        dst[(size_t)c * Rpad + r] = f2bf(tile[tx][ty + i]);
    }
  }
}

// ---------------- bf16 MFMA GEMM: C[M,N] = A[M,K] @ Bt[N,K]^T ----------------
// BMxBN tile, BK=64, 4 waves (2x2), DBUF = double-buffered LDS prefetch.
// EPI: 0 = +bias -> fp32 | 1 = +bias,ReLU -> bf16 | 2 = pad-store -> bf16 (col<Nvalid else 0)
//      3 = cross: x*(acc+bias)+x -> bf16 in place (Cb is both input x and output)
template<int EPI, int BM, int BN, bool DBUF>
__global__ __launch_bounds__(256)
void mfma_gemm(const unsigned short* __restrict__ A, const unsigned short* __restrict__ Bt,
               const float* __restrict__ bias, float* __restrict__ Cf,
               unsigned short* __restrict__ Cb, int M, int N, int K, int Nvalid)
{
  constexpr int BK = 64;
  constexpr int NB = DBUF ? 2 : 1;
  constexpr int WM = BM / 2, WN = BN / 2;
  constexpr int NFM = WM / 16, NFN = WN / 16;
  __shared__ __align__(16) unsigned short As[NB][BM * BK];
  __shared__ __align__(16) unsigned short Bs[NB][BN * BK];

  // XCD-bijective swizzle (requires gridDim.x*gridDim.y % 8 == 0)
  const int nwg  = gridDim.x * gridDim.y;
  const int wgid = blockIdx.y * gridDim.x + blockIdx.x;
  const int q    = nwg >> 3;
  const int sid  = (wgid & 7) * q + (wgid >> 3);
  const int bx   = sid % gridDim.x, by = sid / gridDim.x;

  const int tid  = threadIdx.x;
  const int wave = tid >> 6, lane = tid & 63;
  const int row0 = by * BM;
  const int n0   = bx * BN;
  const int wr = (wave >> 1) * WM, wc = (wave & 1) * WN;
  const int srow = lane >> 3;
  const int gc   = (lane & 7) ^ srow;

  f32x4 acc[NFM][NFN];
#pragma unroll
  for (int m = 0; m < NFM; ++m)
#pragma unroll
    for (int n = 0; n < NFN; ++n)
      acc[m][n] = (f32x4){0.f, 0.f, 0.f, 0.f};

  const size_t abase = (size_t)(row0 + srow) * K + (size_t)gc * 8;
  const size_t bbase = (size_t)(n0   + srow) * K + (size_t)gc * 8;

  auto stage = [&](int buf, int k0) {
#pragma unroll
    for (int i = 0; i < BM / 32; ++i) {
      const int s = wave * (BM / 32) + i;
      gload_lds16(A + abase + (size_t)s * 8 * K + k0, As[buf] + s * 512);
    }
#pragma unroll
    for (int i = 0; i < BN / 32; ++i) {
      const int s = wave * (BN / 32) + i;
      gload_lds16(Bt + bbase + (size_t)s * 8 * K + k0, Bs[buf] + s * 512);
    }
  };

  auto compute = [&](int buf) {
#pragma unroll
    for (int ks = 0; ks < 2; ++ks) {
      short8 af[NFM], bfr[NFN];
#pragma unroll
      for (int m = 0; m < NFM; ++m) {
        const int r  = wr + m * 16 + (lane & 15);
        const int cs = (ks * 4 + (lane >> 4)) ^ (r & 7);
        af[m] = *(const short8*)(As[buf] + r * 64 + cs * 8);
      }
#pragma unroll
      for (int n = 0; n < NFN; ++n) {
        const int r  = wc + n * 16 + (lane & 15);
        const int cs = (ks * 4 + (lane >> 4)) ^ (r & 7);
        bfr[n] = *(const short8*)(Bs[buf] + r * 64 + cs * 8);
      }
#pragma unroll
      for (int m = 0; m < NFM; ++m)
#pragma unroll
        for (int n = 0; n < NFN; ++n)
          acc[m][n] = __builtin_amdgcn_mfma_f32_16x16x32_bf16(af[m], bfr[n], acc[m][n], 0, 0, 0);
    }
  };

  const int nk = K / BK;
  if (!DBUF) {
    for (int t = 0; t < nk; ++t) {
      stage(0, t * BK);
      __syncthreads();
      compute(0);
      __syncthreads();
    }
  } else {
    stage(0, 0);
    __syncthreads();
    int cur = 0;
    for (int t = 0; t + 1 < nk; ++t) {
      stage(cur ^ 1, (t + 1) * BK);
      compute(cur);
      __syncthreads();
      cur ^= 1;
    }
    compute(cur);
  }

  const int l15 = lane & 15, l4 = lane >> 4;
#pragma unroll
  for (int m = 0; m < NFM; ++m) {
#pragma unroll
    for (int n = 0; n < NFN; ++n) {
      const int col = n0 + wc + n * 16 + l15;
      const float bv = (EPI == 2) ? 0.f : bias[col];
#pragma unroll
      for (int r = 0; r < 4; ++r) {
        const int row = row0 + wr + m * 16 + l4 * 4 + r;
        const float v = acc[m][n][r];
        if (EPI == 0) {
          Cf[(size_t)row * N + col] = v + bv;
        } else if (EPI == 1) {
          Cb[(size_t)row * N + col] = f2bf(fmaxf(v + bv, 0.f));
        } else if (EPI == 2) {
          Cb[(size_t)row * N + col] = (col < Nvalid) ? f2bf(v) : (unsigned short)0;
        } else {
          const float x = bf2f(Cb[(size_t)row * N + col]);
          Cb[(size_t)row * N + col] = f2bf(fmaf(x, v + bv, x));
        }
      }
    }
  }
}

// ---------------- L2 normalize rows of H [B,128] -> out fp32 ----------------
__global__ __launch_bounds__(256)
void l2norm_kernel(const float* __restrict__ H, float* __restrict__ out) {
  const int w    = threadIdx.x >> 6;
  const int lane = threadIdx.x & 63;
  const int b    = blockIdx.x * 4 + w;
  const float* hr = H + (size_t)b * 128;
  const float v0 = hr[lane];
  const float v1 = hr[lane + 64];
  float s = v0 * v0 + v1 * v1;
#pragma unroll
  for (int off = 32; off; off >>= 1) s += __shfl_xor(s, off);
  const float r = rsqrtf(fmaxf(s, 1e-12f));
  out[(size_t)b * 128 + lane]      = v0 * r;
  out[(size_t)b * 128 + lane + 64] = v1 * r;
}

extern "C" void kernel_launch(void* const* d_in, const int* in_sizes, int n_in,
                              void* d_out, int out_size, void* d_ws, size_t ws_size,
                              hipStream_t stream)
{
  GatherArgs ga;
  for (int s = 0; s < 15; ++s) {
    ga.idx[s] = (const int*)d_in[s];
    ga.tab[s] = (const float*)d_in[15 + s];
  }
  const float* cross_V = (const float*)d_in[30];  // [1920,100]
  const float* cross_U = (const float*)d_in[31];  // [100,1920]
  const float* cross_b = (const float*)d_in[32];  // [1920]
  const float* W0 = (const float*)d_in[33];       // [1920,512]
  const float* b0 = (const float*)d_in[34];
  const float* W1 = (const float*)d_in[35];       // [512,256]
  const float* b1 = (const float*)d_in[36];
  const float* W2 = (const float*)d_in[37];       // [256,128]
  const float* b2 = (const float*)d_in[38];

  char* w = (char*)d_ws;
  unsigned short* Xb  = (unsigned short*)w; w += (size_t)B_ * F_ * 2;    // [8192,1920] bf16
  unsigned short* t   = (unsigned short*)w; w += (size_t)B_ * 128 * 2;   // [8192,128] bf16 (pad 100->128)
  unsigned short* h0  = (unsigned short*)w; w += (size_t)B_ * 512 * 2;   // [8192,512] bf16
  unsigned short* h1  = (unsigned short*)w; w += (size_t)B_ * 256 * 2;   // [8192,256] bf16
  float*          h2  = (float*)w;          w += (size_t)B_ * 128 * 4;   // [8192,128] fp32
  unsigned short* Vt  = (unsigned short*)w; w += (size_t)128 * F_ * 2;   // [128,1920]
  unsigned short* Ut  = (unsigned short*)w; w += (size_t)F_ * 128 * 2;   // [1920,128]
  unsigned short* Wt0 = (unsigned short*)w; w += (size_t)512 * F_ * 2;   // [512,1920]
  unsigned short* Wt1 = (unsigned short*)w; w += (size_t)256 * 512 * 2;  // [256,512]
  unsigned short* Wt2 = (unsigned short*)w; w += (size_t)128 * 256 * 2;  // [128,256]

  const dim3 tb(256);

  // weight-transpose descriptors (fp32 -> bf16, K-major, zero-padded)
  TransBatch tbt;
  const float* srcs[5] = {cross_V, cross_U, W0, W1, W2};
  unsigned short* dsts[5] = {Vt, Ut, Wt0, Wt1, Wt2};
  const int Rs[5]  = {F_, P_, F_, 512, 256};
  const int Cs[5]  = {P_, F_, 512, 256, 128};
  const int Cp[5]  = {128, F_, 512, 256, 128};
  const int Rp[5]  = {F_, 128, F_, 512, 256};
  int acc_t = 0;
  for (int i = 0; i < 5; ++i) {
    tbt.src[i] = srcs[i]; tbt.dst[i] = dsts[i];
    tbt.R[i] = Rs[i]; tbt.C[i] = Cs[i]; tbt.Cpad[i] = Cp[i]; tbt.Rpad[i] = Rp[i];
    tbt.tiles_c[i] = Cp[i] / 32;
    tbt.tile0[i] = acc_t;
    acc_t += (Rp[i] / 32) * (Cp[i] / 32);
  }
  tbt.tile0[5] = acc_t;

  // 1) gather + pool -> Xb, and all weight transposes, in one launch
  prep_kernel<<<NGATHER + acc_t, tb, 0, stream>>>(ga, Xb, tbt);
  // 2) t = Xb @ V            [8192,128(100 valid)]   grid 2x256=512
  mfma_gemm<2, 32, 64, true><<<dim3(2, B_ / 32), tb, 0, stream>>>(
      Xb, Vt, nullptr, nullptr, t, B_, 128, F_, P_);
  // 3) Xb = x*(t @ U + b)+x  [8192,1920] in place    grid 15x64=960 (K=128: no dbuf)
  mfma_gemm<3, 128, 128, false><<<dim3(F_ / 128, B_ / 128), tb, 0, stream>>>(
      t, Ut, cross_b, nullptr, Xb, B_, F_, 128, F_);
  // 4) h0 = relu(Xb @ W0 + b0)   [8192,512]          grid 4x128=512
  mfma_gemm<1, 64, 128, true><<<dim3(512 / 128, B_ / 64), tb, 0, stream>>>(
      Xb, Wt0, b0, nullptr, h0, B_, 512, F_, 512);
  // 5) h1 = relu(h0 @ W1 + b1)   [8192,256]          grid 4x128=512
  mfma_gemm<1, 64, 64, true><<<dim3(256 / 64, B_ / 64), tb, 0, stream>>>(
      h0, Wt1, b1, nullptr, h1, B_, 256, 512, 256);
  // 6) h2 = h1 @ W2 + b2         [8192,128] fp32     grid 2x256=512
  mfma_gemm<0, 32, 64, true><<<dim3(128 / 64, B_ / 32), tb, 0, stream>>>(
      h1, Wt2, b2, h2, nullptr, B_, 128, 256, 128);
  // 7) L2 normalize -> out
  l2norm_kernel<<<B_ / 4, tb, 0, stream>>>(h2, (float*)d_out);
}